// Round 7
// baseline (810.758 us; speedup 1.0000x reference)
//
#include <hip/hip_runtime.h>
#include <hip/hip_bf16.h>
#include <hip/hip_cooperative_groups.h>

namespace cg = cooperative_groups;

// Affine collapse: B(v)=v*M+c with M = fc1_W^T @ fc2_W^T, T = I-M.
//   inv_total = x*(I-T^5) + bias ;  nxt = x - inv_total
//   out_i = x*Bout_i + f_i,  Bout_i^T = compW_i * Delta_i^T, Delta_i = T^{i-1}-T^i
// One main GEMM [8192 x 6144 x 1024] computes invtot + all five out_i.
// Loss sign-factorization: c[n,j] = sign(out[n,j]) * r[n], r[n]=S[n]/(32*sqrt(Q[n]))
// -> gemm_main stores 1 SIGN BIT per out element via __ballot + per-row S,Q.
// Main GEMM: round-4 known-good 128^2 m97-structure core (158us, 76 VGPR, 2 blk/CU).
// THIS ROUND: the entire matrix-power setup chain (splitk, mbuild, T2, T3/T4,
// T5+deltas, gemvs, biasall, Bout batch = 8 dispatches) is fused into ONE
// cooperative kernel (512 blocks, grid.sync between 5 stages) to kill the
// per-dispatch fixed cost (launch+ramp+tail ~15-25us each). 13 -> 6 dispatches.

#define NR 8192
#define DD 1024
#define HH 4096
#define NL 5
#define MSZ (DD * DD)

using bf16 = __hip_bfloat16;
typedef __attribute__((ext_vector_type(8))) short bf16x8;
typedef __attribute__((ext_vector_type(4))) float f32x4;

// ---------------- fused prep: all f32->bf16 conversions + zero-init ----------------

__device__ __forceinline__ void cvt4(const float* __restrict__ in, bf16* __restrict__ out, int i) {
  float4 v = ((const float4*)in)[i];
  union { bf16 b[4]; uint2 u; } u;
  u.b[0] = __float2bfloat16(v.x); u.b[1] = __float2bfloat16(v.y);
  u.b[2] = __float2bfloat16(v.z); u.b[3] = __float2bfloat16(v.w);
  ((uint2*)out)[i] = u.u;
}

#define NX4 (NR * DD / 4)
#define NF4 (DD * HH / 4)
#define NC4 (NL * MSZ / 4)
#define NS4 ((NL * DD + 2 * NL * NR) / 4)
#define NE4 (DD)  /* 4*DD floats / 4 */

__global__ void prep_kernel(const float* __restrict__ x, const float* __restrict__ fc2_W,
                            const float* __restrict__ comp_W,
                            bf16* __restrict__ x_bf, bf16* __restrict__ fc2_bf,
                            bf16* __restrict__ compW_bf,
                            float* __restrict__ stats, float* __restrict__ ebuf) {
  int i = blockIdx.x * 256 + threadIdx.x;
  const int stride = gridDim.x * 256;
  const int total = NX4 + NF4 + NC4 + NS4 + NE4;
  const float4 z4 = {0.f, 0.f, 0.f, 0.f};
  for (; i < total; i += stride) {
    if (i < NX4) cvt4(x, x_bf, i);
    else if (i < NX4 + NF4) cvt4(fc2_W, fc2_bf, i - NX4);
    else if (i < NX4 + NF4 + NC4) cvt4(comp_W, compW_bf, i - NX4 - NF4);
    else if (i < NX4 + NF4 + NC4 + NS4) ((float4*)stats)[i - NX4 - NF4 - NC4] = z4;
    else ((float4*)ebuf)[i - NX4 - NF4 - NC4 - NS4] = z4;
  }
}

// fc1 transpose (1024 blocks) + cvec (1024 blocks) fused into one dispatch
__global__ void smallprep_kernel(const float* __restrict__ fc1_W, bf16* __restrict__ fc1T,
                                 const float* __restrict__ fc1_b, const float* __restrict__ fc2_W,
                                 const float* __restrict__ fc2_b, float* __restrict__ cvec) {
  if (blockIdx.x < 1024) {
    __shared__ bf16 tile[64][74];
    const int c0 = (blockIdx.x & 15) * 64;
    const int r0 = (blockIdx.x >> 4) * 64;
    const int col = threadIdx.x & 63;
    const int row4 = threadIdx.x >> 6;
    #pragma unroll
    for (int j = 0; j < 16; ++j) {
      int r = row4 * 16 + j;
      tile[r][col] = __float2bfloat16(fc1_W[(size_t)(r0 + r) * DD + c0 + col]);
    }
    __syncthreads();
    #pragma unroll
    for (int j = 0; j < 16; ++j) {
      int r = row4 * 16 + j;
      fc1T[(size_t)(c0 + r) * HH + r0 + col] = tile[col][r];
    }
  } else {
    const int j = blockIdx.x - 1024;
    float s = 0.f;
    for (int k = threadIdx.x; k < HH; k += 256) s += fc1_b[k] * fc2_W[(size_t)j * HH + k];
    for (int o = 32; o; o >>= 1) s += __shfl_down(s, o);
    __shared__ float red[4];
    if ((threadIdx.x & 63) == 0) red[threadIdx.x >> 6] = s;
    __syncthreads();
    if (threadIdx.x == 0) cvec[j] = red[0] + red[1] + red[2] + red[3] + fc2_b[j];
  }
}

// ---------------- GEMM cores: C[m,n] = sum_k A[m,k]*B[n,k] ----------------
// LDS tiles row-major, 128B pitch, chunk-XOR swizzled: physical 16B-chunk c of row r
// holds logical chunk c ^ (r & 7). global_load_lds dest = wave-uniform base + lane*16B
// -> lane covers (row = lane>>3, phys chunk = lane&7), so source logical chunk =
// (lane&7)^(lane>>3). Reads: fragment rows have row&7 == lane&7, so the unswizzled
// chunk is (logical ^ (lane&7)). Measured 0 LDS bank conflicts with this pattern.

__device__ __forceinline__ void async16(const bf16* g, bf16* l) {
  __builtin_amdgcn_global_load_lds(
      (const __attribute__((address_space(1))) void*)g,
      (__attribute__((address_space(3))) void*)l, 16, 0, 0);
}

// 64x64 tile, 4 waves of 32x32 (2x2 frags) — setup-chain stages
__device__ __forceinline__ void gemm_core64(
    const bf16* __restrict__ A, const bf16* __restrict__ B,
    int kBeg, int kEnd, int lda, int ldb, int bm, int bn,
    bf16* As, bf16* Bs, f32x4 acc[2][2])
{
  const int tid  = threadIdx.x;
  const int lane = tid & 63;
  const int wave = tid >> 6;
  const int wm = (wave & 1) * 32;
  const int wn = (wave >> 1) * 32;
  const int lr = lane >> 3;
  const int lcol = ((lane & 7) ^ lr) * 8;
  const bf16* gA = A + (size_t)(bm + wave * 16 + lr) * lda + lcol;
  const bf16* gB = B + (size_t)(bn + wave * 16 + lr) * ldb + lcol;
  bf16* lA = As + wave * 16 * 64;
  bf16* lB = Bs + wave * 16 * 64;

  for (int k0 = kBeg; k0 < kEnd; k0 += 64) {
    #pragma unroll
    for (int it = 0; it < 2; ++it) {
      async16(gA + (size_t)(it * 8) * lda + k0, lA + it * 8 * 64);
      async16(gB + (size_t)(it * 8) * ldb + k0, lB + it * 8 * 64);
    }
    __syncthreads();
    #pragma unroll
    for (int ks = 0; ks < 2; ++ks) {
      bf16x8 av[2], bv[2];
      #pragma unroll
      for (int i = 0; i < 2; ++i) {
        const int rr = i * 16 + (lane & 15);
        const int cc = ((ks * 4 + (lane >> 4)) ^ (lane & 7)) * 8;
        av[i] = *(const bf16x8*)(As + (wm + rr) * 64 + cc);
        bv[i] = *(const bf16x8*)(Bs + (wn + rr) * 64 + cc);
      }
      #pragma unroll
      for (int i = 0; i < 2; ++i)
        #pragma unroll
        for (int j = 0; j < 2; ++j)
          acc[i][j] = __builtin_amdgcn_mfma_f32_16x16x32_bf16(av[i], bv[j], acc[i][j], 0, 0, 0);
    }
    __syncthreads();
  }
}

// ---------------- cooperative mega kernel: the whole matrix-power chain ----------------
// 512 blocks x 256 thr, 5 grid.sync stages:
//  A : Cp[kh] = split-K(2) partials of M = fc1T·fc2b            (512 tile-jobs)
//  A2: combine -> M(Dbank0), T(Pw0), Tt(Ttb0)                   (256 jobs)
//  B : T2 dual (Pw1 + Ttb1)  ||  e2 = T^T c                     (256 + 16 jobs)
//  C : T3 = T2·T, T4 = T2·T2                                    (512 jobs)
//  D : T5 acc -> Delta2..5(Dbank1..4) + Bbig0=(I-T5)^T || e3..e5 (256 + 48 jobs)
//  E : Bout_z^T = compW_z·Delta_z^T (Bbig1..5)  + biasall        (1280 + 6144 jobs)

__global__ __launch_bounds__(256, 2)
void mega_kernel(const bf16* __restrict__ fc1T, const bf16* __restrict__ fc2b,
                 const float* __restrict__ cvec, const bf16* __restrict__ compWb,
                 const float* __restrict__ comp_W, const float* __restrict__ comp_b,
                 float* __restrict__ Cp, bf16* __restrict__ Dbank, bf16* __restrict__ Pw,
                 bf16* __restrict__ Ttb, bf16* __restrict__ Bbig,
                 float* __restrict__ ebuf, float* __restrict__ biasall) {
  cg::grid_group grid = cg::this_grid();
  __shared__ char smem[16640];                  // As+Bs (16384) / float tile[64][65] (16640)
  bf16* As = (bf16*)smem;
  bf16* Bs = (bf16*)(smem + 8192);
  const int b = blockIdx.x;
  const int lane = threadIdx.x & 63;
  const int wm = ((threadIdx.x >> 6) & 1) * 32;
  const int wn = ((threadIdx.x >> 6) >> 1) * 32;

  // ---- stage A ----
  {
    const int t = b >> 1, kh = b & 1;
    const int m0 = (t >> 4) * 64, n0 = (t & 15) * 64;
    f32x4 acc[2][2] = {};
    gemm_core64(fc1T, fc2b, kh * (HH / 2), (kh + 1) * (HH / 2), HH, HH, m0, n0, As, Bs, acc);
    float* C = Cp + (size_t)kh * MSZ;
    #pragma unroll
    for (int i = 0; i < 2; ++i)
      #pragma unroll
      for (int j = 0; j < 2; ++j) {
        const int col = n0 + wn + j * 16 + (lane & 15);
        #pragma unroll
        for (int r = 0; r < 4; ++r) {
          const int row = m0 + wm + i * 16 + (lane >> 4) * 4 + r;
          C[(size_t)row * DD + col] = acc[i][j][r];
        }
      }
  }
  grid.sync();
  // ---- stage A2 ----
  if (b < 256) {
    float (*tile)[65] = (float(*)[65])smem;
    const int m0 = (b >> 4) * 64, n0 = (b & 15) * 64;
    const int tn = threadIdx.x & 63, tm4 = threadIdx.x >> 6;
    #pragma unroll
    for (int j = 0; j < 16; ++j) {
      const int m = tm4 * 16 + j;
      const size_t idx = (size_t)(m0 + m) * DD + n0 + tn;
      const float v = Cp[idx] + Cp[MSZ + idx];
      tile[m][tn] = v;
      const float d = ((m0 + m) == (n0 + tn)) ? 1.f : 0.f;
      Dbank[idx] = __float2bfloat16(v);          // M = Delta_1
      Pw[idx]    = __float2bfloat16(d - v);      // T
    }
    __syncthreads();
    #pragma unroll
    for (int j = 0; j < 16; ++j) {
      const int r = tm4 * 16 + j;
      const float v = tile[tn][r];
      const size_t idx = (size_t)(n0 + r) * DD + m0 + tn;
      const float d = ((n0 + r) == (m0 + tn)) ? 1.f : 0.f;
      Ttb[idx] = __float2bfloat16(d - v);        // T^T
    }
  }
  grid.sync();
  // ---- stage B ----
  if (b < 256) {
    const int m0 = (b >> 4) * 64, n0 = (b & 15) * 64;
    f32x4 acc[2][2] = {};
    gemm_core64(Pw, Ttb, 0, DD, DD, DD, m0, n0, As, Bs, acc);
    #pragma unroll
    for (int i = 0; i < 2; ++i)
      #pragma unroll
      for (int j = 0; j < 2; ++j) {
        const int col = n0 + wn + j * 16 + (lane & 15);
        const int row0 = m0 + wm + i * 16 + (lane >> 4) * 4;
        union { bf16 h[4]; uint2 u; } pk;
        #pragma unroll
        for (int r = 0; r < 4; ++r) {
          bf16 v = __float2bfloat16(acc[i][j][r]);
          pk.h[r] = v;
          Pw[MSZ + (size_t)(row0 + r) * DD + col] = v;        // T2
        }
        *(uint2*)(&Ttb[MSZ + (size_t)col * DD + row0]) = pk.u; // T2^T
      }
  } else if (b < 272) {
    const int idx = b - 256, jg = idx & 3, kg = idx >> 2;
    const int j = jg * 256 + threadIdx.x, k0 = kg * 256;
    float s = 0.f;
    #pragma unroll 8
    for (int k = k0; k < k0 + 256; ++k) s += cvec[k] * __bfloat162float(Pw[(size_t)k * DD + j]);
    atomicAdd(&ebuf[j], s);                                    // e2
  }
  grid.sync();
  // ---- stage C ----
  {
    const int z = b >> 8, t = b & 255;
    const int m0 = (t >> 4) * 64, n0 = (t & 15) * 64;
    f32x4 acc[2][2] = {};
    gemm_core64(Pw + MSZ, Ttb + (size_t)z * MSZ, 0, DD, DD, DD, m0, n0, As, Bs, acc);
    bf16* C = Pw + (size_t)(2 + z) * MSZ;                      // T3 / T4
    #pragma unroll
    for (int i = 0; i < 2; ++i)
      #pragma unroll
      for (int j = 0; j < 2; ++j) {
        const int col = n0 + wn + j * 16 + (lane & 15);
        #pragma unroll
        for (int r = 0; r < 4; ++r) {
          const int row = m0 + wm + i * 16 + (lane >> 4) * 4 + r;
          C[(size_t)row * DD + col] = __float2bfloat16(acc[i][j][r]);
        }
      }
  }
  grid.sync();
  // ---- stage D ----
  if (b < 256) {
    const int m0 = (b >> 4) * 64, n0 = (b & 15) * 64;
    f32x4 acc[2][2] = {};
    gemm_core64(Pw + 3 * MSZ, Ttb, 0, DD, DD, DD, m0, n0, As, Bs, acc);   // T5
    bf16* Dl = Dbank + MSZ;
    #pragma unroll
    for (int i = 0; i < 2; ++i)
      #pragma unroll
      for (int j = 0; j < 2; ++j) {
        const int col = n0 + wn + j * 16 + (lane & 15);
        const int row0 = m0 + wm + i * 16 + (lane >> 4) * 4;
        union { bf16 h[4]; uint2 u; } pk;
        #pragma unroll
        for (int r = 0; r < 4; ++r) {
          const size_t idx = (size_t)(row0 + r) * DD + col;
          const float t1 = __bfloat162float(Pw[idx]);
          const float t2 = __bfloat162float(Pw[MSZ + idx]);
          const float t3 = __bfloat162float(Pw[2 * MSZ + idx]);
          const float t4 = __bfloat162float(Pw[3 * MSZ + idx]);
          const float t5 = acc[i][j][r];
          Dl[idx]           = __float2bfloat16(t1 - t2);
          Dl[MSZ + idx]     = __float2bfloat16(t2 - t3);
          Dl[2 * MSZ + idx] = __float2bfloat16(t3 - t4);
          Dl[3 * MSZ + idx] = __float2bfloat16(t4 - t5);
          pk.h[r] = __float2bfloat16((((row0 + r) == col) ? 1.f : 0.f) - t5);
        }
        *(uint2*)(&Bbig[(size_t)col * DD + row0]) = pk.u;      // (I-T5)^T
      }
  } else if (b < 304) {
    const int z = 1 + (b - 256) / 16, idx = (b - 256) % 16, jg = idx & 3, kg = idx >> 2;
    const int j = jg * 256 + threadIdx.x, k0 = kg * 256;
    const bf16* P = Pw + (size_t)z * MSZ;                      // T2/T3/T4
    float s = 0.f;
    #pragma unroll 8
    for (int k = k0; k < k0 + 256; ++k) s += cvec[k] * __bfloat162float(P[(size_t)k * DD + j]);
    atomicAdd(&ebuf[(size_t)z * DD + j], s);                   // e3..e5
  }
  grid.sync();
  // ---- stage E ----
  for (int jb = b; jb < 1280; jb += 512) {
    const int z = jb >> 8, t = jb & 255;
    const int m0 = (t >> 4) * 64, n0 = (t & 15) * 64;
    f32x4 acc[2][2] = {};
    gemm_core64(compWb + (size_t)z * MSZ, Dbank + (size_t)z * MSZ, 0, DD, DD, DD,
                m0, n0, As, Bs, acc);
    bf16* C = Bbig + (size_t)(1 + z) * MSZ;                    // Bout_z^T
    #pragma unroll
    for (int i = 0; i < 2; ++i)
      #pragma unroll
      for (int j = 0; j < 2; ++j) {
        const int col = n0 + wn + j * 16 + (lane & 15);
        #pragma unroll
        for (int r = 0; r < 4; ++r) {
          const int row = m0 + wm + i * 16 + (lane >> 4) * 4 + r;
          C[(size_t)row * DD + col] = __float2bfloat16(acc[i][j][r]);
        }
      }
  }
  // biasall: 6144 outputs, 12 per block
  float* red = (float*)smem;
  for (int q = 0; q < 12; ++q) {
    const int o = b * 12 + q;
    const int z = o >> 10, j = o & 1023;
    __syncthreads();
    if (z == 0) {
      if (threadIdx.x == 0)
        biasall[j] = cvec[j] + ebuf[j] + ebuf[DD + j] + ebuf[2 * DD + j] + ebuf[3 * DD + j];
    } else {
      const int i = z - 1;
      const float* e = (i == 0) ? cvec : ebuf + (size_t)(i - 1) * DD;
      const float* wr2 = comp_W + (size_t)i * MSZ + (size_t)j * DD;
      float s = 0.f;
      for (int k = threadIdx.x; k < DD; k += 256) s += e[k] * wr2[k];
      for (int o2 = 32; o2; o2 >>= 1) s += __shfl_down(s, o2);
      if ((threadIdx.x & 63) == 0) red[threadIdx.x >> 6] = s;
      __syncthreads();
      if (threadIdx.x == 0)
        biasall[(size_t)z * DD + j] = red[0] + red[1] + red[2] + red[3] + comp_b[(size_t)i * DD + j];
    }
  }
}

// ---------------- main GEMM (round-4 known-good 128^2 core) ----------------

__device__ __forceinline__ void gemm_core_async(
    const bf16* __restrict__ A, const bf16* __restrict__ B,
    int kBeg, int kEnd, int lda, int ldb, int bm, int bn,
    bf16* As, bf16* Bs, f32x4 acc[4][4])
{
  const int tid  = threadIdx.x;
  const int lane = tid & 63;
  const int wave = tid >> 6;
  const int wm = (wave & 1) * 64;
  const int wn = (wave >> 1) * 64;
  const int lr = lane >> 3;                 // row within 8-row DMA group
  const int lcol = ((lane & 7) ^ lr) * 8;   // swizzled source chunk
  const bf16* gA = A + (size_t)(bm + wave * 32 + lr) * lda + lcol;
  const bf16* gB = B + (size_t)(bn + wave * 32 + lr) * ldb + lcol;
  bf16* lA = As + wave * 32 * 64;           // wave-uniform LDS bases
  bf16* lB = Bs + wave * 32 * 64;

  for (int k0 = kBeg; k0 < kEnd; k0 += 64) {
    #pragma unroll
    for (int it = 0; it < 4; ++it) {
      async16(gA + (size_t)(it * 8) * lda + k0, lA + it * 8 * 64);
      async16(gB + (size_t)(it * 8) * ldb + k0, lB + it * 8 * 64);
    }
    __syncthreads();   // compiler emits vmcnt(0) drain before barrier
    #pragma unroll
    for (int ks = 0; ks < 2; ++ks) {
      bf16x8 av[4], bv[4];
      #pragma unroll
      for (int i = 0; i < 4; ++i) {
        const int rr = i * 16 + (lane & 15);
        const int cc = ((ks * 4 + (lane >> 4)) ^ (lane & 7)) * 8;  // unswizzle
        av[i] = *(const bf16x8*)(As + (wm + rr) * 64 + cc);
        bv[i] = *(const bf16x8*)(Bs + (wn + rr) * 64 + cc);
      }
      #pragma unroll
      for (int i = 0; i < 4; ++i)
        #pragma unroll
        for (int j = 0; j < 4; ++j)
          acc[i][j] = __builtin_amdgcn_mfma_f32_16x16x32_bf16(av[i], bv[j], acc[i][j], 0, 0, 0);
    }
    __syncthreads();
  }
}

#define GEMM_PROLOGUE \
  alignas(16) __shared__ bf16 As[128 * 64]; \
  alignas(16) __shared__ bf16 Bs[128 * 64]; \
  f32x4 acc[4][4] = {}; \
  const int lane = threadIdx.x & 63; \
  const int wm = ((threadIdx.x >> 6) & 1) * 64; \
  const int wn = ((threadIdx.x >> 6) >> 1) * 64;

// main GEMM [8192 x 6144 x 1024]: cols 0..1023 -> invtot/nxt; cols 1024+ -> out_z,
// reduced to per-row S,Q (shuffle+atomics) + 1 SIGN BIT per element (ballot words).
// Sign word layout: sgn[(((z*64+rb)*8+cb)*4+wave)*64 + i*16+j*4+r] (u64),
// bit (rg*16+c15) = sign(out[row,col]).
__global__ __launch_bounds__(256, 2)
void gemm_main(const bf16* __restrict__ A, const bf16* __restrict__ Bb,
               const float* __restrict__ biasall, const bf16* __restrict__ xb,
               float* __restrict__ invtot, float* __restrict__ nxtf,
               unsigned long long* __restrict__ sgn,
               float* __restrict__ Srow, float* __restrict__ Qrow) {
  GEMM_PROLOGUE
  const int bm = blockIdx.y * 128, bn = blockIdx.x * 128;
  gemm_core_async(A, Bb + (size_t)(bn >> 10) * MSZ, 0, DD, DD, DD, bm, bn & (DD - 1), As, Bs, acc);

  if (bn < DD) {
    #pragma unroll
    for (int i = 0; i < 4; ++i)
      #pragma unroll
      for (int j = 0; j < 4; ++j) {
        const int col = bn + wn + j * 16 + (lane & 15);
        const float bj = biasall[col];
        #pragma unroll
        for (int r = 0; r < 4; ++r) {
          const int row = bm + wm + i * 16 + (lane >> 4) * 4 + r;
          const float v = acc[i][j][r] + bj;
          const size_t idx = (size_t)row * DD + col;
          invtot[idx] = v;
          nxtf[idx] = __bfloat162float(xb[idx]) - v;   // xb rows are L2-hot (A-tile)
        }
      }
  } else {
    const int z = (bn >> 10) - 1;
    const int rb = bm >> 7;
    const int cb = (bn & (DD - 1)) >> 7;
    const int wave = threadIdx.x >> 6;
    unsigned long long keep = 0ULL;
    float sv[4][4] = {}, qv[4][4] = {};
    #pragma unroll
    for (int i = 0; i < 4; ++i)
      #pragma unroll
      for (int j = 0; j < 4; ++j) {
        const int colg = bn + wn + j * 16 + (lane & 15);
        const float bj = biasall[colg];
        #pragma unroll
        for (int r = 0; r < 4; ++r) {
          const float v = acc[i][j][r] + bj;
          const unsigned long long bal = __ballot(v < 0.f);
          if (lane == i * 16 + j * 4 + r) keep = bal;   // idx compile-time per unroll
          sv[i][r] += v;
          qv[i][r] += v * v;
        }
      }
    const size_t wbase = ((((size_t)z * 64 + rb) * 8 + cb) * 4 + wave) * 64;
    sgn[wbase + lane] = keep;                            // 512 B/wave, coalesced
    #pragma unroll
    for (int i = 0; i < 4; ++i)
      #pragma unroll
      for (int r = 0; r < 4; ++r) {
        float s = sv[i][r], q = qv[i][r];
        #pragma unroll
        for (int off = 1; off < 16; off <<= 1) { s += __shfl_xor(s, off); q += __shfl_xor(q, off); }
        if ((lane & 15) == 0) {
          const int row = bm + wm + i * 16 + (lane >> 4) * 4 + r;
          atomicAdd(&Srow[(size_t)z * NR + row], s);
          atomicAdd(&Qrow[(size_t)z * NR + row], q);
        }
      }
  }
}

// ---------------- loss ----------------

// Dtot[z][col] += sum_n |c[n,col]-c[n-1,col]|, c[n,col] = +-r[n] by sign bit.
__global__ void losssign_kernel(const unsigned long long* __restrict__ sgn,
                                const float* __restrict__ Srow, const float* __restrict__ Qrow,
                                float* __restrict__ Dtot) {
  const int z = blockIdx.y;
  const int cg = blockIdx.x;            // 64-col group
  const int n0 = blockIdx.z * 1024;
  __shared__ float rsh[1025];
  const float* S = Srow + (size_t)z * NR;
  const float* Q = Qrow + (size_t)z * NR;
  for (int t = threadIdx.x; t < 1025; t += 256) {
    int n = n0 + t; if (n > NR - 1) n = NR - 1;
    rsh[t] = S[n] * rsqrtf(Q[n]) * 0.03125f;   // r[n] = S/(32*sqrt(Q))
  }
  __syncthreads();
  const int c = threadIdx.x & 63;
  const int q = threadIdx.x >> 6;
  const int col = cg * 64 + c;
  const int cb = col >> 7;
  const int wsel = (col >> 6) & 1;      // wn half -> wave bit 1
  const int jf = (col >> 4) & 3;
  const int c15 = col & 15;
  const size_t zbase = (size_t)z * 64 * 8 * 4 * 64;
  const int ns = n0 + q * 256;
  int ne = ns + 256; if (ne > NR - 1) ne = NR - 1;

  auto cval = [&](int n) -> float {
    const int rbk = n >> 7, nl = n & 127;
    const int wave = (nl >> 6) | (wsel << 1);
    const int i = (nl >> 4) & 3, rg = (nl >> 2) & 3, r = nl & 3;
    const size_t widx = zbase + ((((size_t)rbk * 8 + cb) * 4 + wave) * 64)
                      + i * 16 + jf * 4 + r;
    const unsigned long long wv = sgn[widx];
    const float rv = rsh[n - n0];
    return ((wv >> (rg * 16 + c15)) & 1ULL) ? -rv : rv;
  };

  float d = 0.f;
  float cprev = cval(ns);
  for (int n = ns + 1; n <= ne; ++n) {
    const float cn = cval(n);
    d += fabsf(cn - cprev);
    cprev = cn;
  }
  atomicAdd(&Dtot[z * DD + col], d);
}

__global__ void writeloss_kernel(const float* __restrict__ Dtot, float* __restrict__ out) {
  int idx = blockIdx.x * 256 + threadIdx.x;
  int j = idx & (DD - 1);
  out[idx] = Dtot[j] + Dtot[DD + j] + Dtot[2 * DD + j] + Dtot[3 * DD + j] + Dtot[4 * DD + j];
}

// ---------------- launch ----------------

extern "C" void kernel_launch(void* const* d_in, const int* in_sizes, int n_in,
                              void* d_out, int out_size, void* d_ws, size_t ws_size,
                              hipStream_t stream) {
  const float* x      = (const float*)d_in[0];
  const float* fc1_W  = (const float*)d_in[1];
  const float* fc1_b  = (const float*)d_in[2];
  const float* fc2_W  = (const float*)d_in[3];
  const float* fc2_b  = (const float*)d_in[4];
  const float* comp_W = (const float*)d_in[5];
  const float* comp_b = (const float*)d_in[6];

  float* invtot  = (float*)d_out;
  float* nxtf    = invtot + (size_t)NR * DD;
  float* lossout = invtot + (size_t)2 * NR * DD;

  char* w = (char*)d_ws;
  auto alloc = [&](size_t bytes) { char* p = w; w += (bytes + 255) & ~(size_t)255; return p; };
  bf16* x_bf     = (bf16*)alloc((size_t)NR * DD * 2);          // 16 MB
  bf16* fc1T_bf  = (bf16*)alloc((size_t)DD * HH * 2);          // 8 MB
  bf16* fc2_bf   = (bf16*)alloc((size_t)DD * HH * 2);          // 8 MB
  bf16* compW_bf = (bf16*)alloc((size_t)NL * MSZ * 2);         // 10 MB
  bf16* Dbank    = (bf16*)alloc((size_t)5 * MSZ * 2);          // [Delta1=M, D2..D5] 10 MB
  bf16* Tt_buf   = (bf16*)alloc((size_t)2 * MSZ * 2);          // [Tt, T2t] 4 MB
  bf16* Pw       = (bf16*)alloc((size_t)4 * MSZ * 2);          // [T, T2, T3, T4] 8 MB
  bf16* Bbig     = (bf16*)alloc((size_t)6 * MSZ * 2);          // 12 MB
  unsigned long long* sgn = (unsigned long long*)alloc((size_t)NL * 64 * 8 * 4 * 64 * 8); // 5 MB
  float* Cp      = (float*)alloc((size_t)2 * MSZ * 4);         // 8 MB split-K partials
  float* cvec    = (float*)alloc(DD * 4);
  float* ebuf    = (float*)alloc((size_t)4 * DD * 4);
  float* biasall = (float*)alloc((size_t)6 * DD * 4);
  float* stats   = (float*)alloc((size_t)(NL * DD + 2 * NL * NR) * 4);
  float* Dtot = stats;
  float* Srow = stats + NL * DD;
  float* Qrow = Srow + (size_t)NL * NR;
  (void)ws_size; (void)in_sizes; (void)n_in; (void)out_size;

  // 1. bulk conversions + zero-init
  prep_kernel<<<2048, 256, 0, stream>>>(x, fc2_W, comp_W, x_bf, fc2_bf, compW_bf, stats, ebuf);
  // 2. fc1 transpose + cvec (fused)
  smallprep_kernel<<<2048, 256, 0, stream>>>(fc1_W, fc1T_bf, fc1_b, fc2_W, fc2_b, cvec);
  // 3. the whole matrix-power chain in ONE cooperative dispatch
  {
    void* args[] = {
      (void*)&fc1T_bf, (void*)&fc2_bf, (void*)&cvec, (void*)&compW_bf,
      (void*)&comp_W, (void*)&comp_b, (void*)&Cp, (void*)&Dbank, (void*)&Pw,
      (void*)&Tt_buf, (void*)&Bbig, (void*)&ebuf, (void*)&biasall };
    hipLaunchCooperativeKernel((void*)mega_kernel, dim3(512), dim3(256), args, 0, stream);
  }
  // 4. main GEMM (round-4 128^2 core)
  gemm_main<<<dim3(6 * DD / 128, NR / 128), 256, 0, stream>>>(
      x_bf, Bbig, biasall, x_bf, invtot, nxtf, sgn, Srow, Qrow);
  // 5-6. loss
  losssign_kernel<<<dim3(16, NL, 8), 256, 0, stream>>>(sgn, Srow, Qrow, Dtot);
  writeloss_kernel<<<MSZ / 256, 256, 0, stream>>>(Dtot, lossout);
}

// Round 8
// 460.848 us; speedup vs baseline: 1.7593x; 1.7593x over previous
//
#include <hip/hip_runtime.h>
#include <hip/hip_bf16.h>

// Affine collapse: B(v)=v*M+c with M = fc1_W^T @ fc2_W^T, T = I-M.
//   inv_total = x*(I-T^5) + bias ;  nxt = x - inv_total
//   out_i = x*Bout_i + f_i,  Bout_i^T = compW_i * Delta_i^T, Delta_i = T^{i-1}-T^i
// One main GEMM [8192 x 6144 x 1024] computes invtot + all five out_i.
// Loss sign-factorization: c[n,j] = sign(out[n,j]) * r[n], r[n]=S[n]/(32*sqrt(Q[n]))
// -> gemm_main stores 1 SIGN BIT per out element via __ballot + per-row S,Q.
// Main GEMM: round-4 known-good 128^2 m97-structure core (158us, 76 VGPR).
// Round-7 lesson: cooperative grid.sync mega-fusion = 65 TF (device-scope fences
// across 8 non-coherent XCD L2s dominate). Reverted. THIS ROUND: merge only
// INDEPENDENT dispatches by grid partitioning (no new sync): 14 -> 10 dispatches.

#define NR 8192
#define DD 1024
#define HH 4096
#define NL 5
#define MSZ (DD * DD)

using bf16 = __hip_bfloat16;
typedef __attribute__((ext_vector_type(8))) short bf16x8;
typedef __attribute__((ext_vector_type(4))) float f32x4;

// ---------------- prepall: bulk cvt + zero || fc1 transpose || cvec (one dispatch) ----

__device__ __forceinline__ void cvt4(const float* __restrict__ in, bf16* __restrict__ out, int i) {
  float4 v = ((const float4*)in)[i];
  union { bf16 b[4]; uint2 u; } u;
  u.b[0] = __float2bfloat16(v.x); u.b[1] = __float2bfloat16(v.y);
  u.b[2] = __float2bfloat16(v.z); u.b[3] = __float2bfloat16(v.w);
  ((uint2*)out)[i] = u.u;
}

#define NX4 (NR * DD / 4)
#define NF4 (DD * HH / 4)
#define NC4 (NL * MSZ / 4)
#define NS4 ((NL * DD + 2 * NL * NR) / 4)
#define NE4 (DD)  /* 4*DD floats / 4 */

__global__ void prepall_kernel(const float* __restrict__ x, const float* __restrict__ fc2_W,
                               const float* __restrict__ comp_W, const float* __restrict__ fc1_W,
                               const float* __restrict__ fc1_b, const float* __restrict__ fc2_b,
                               bf16* __restrict__ x_bf, bf16* __restrict__ fc2_bf,
                               bf16* __restrict__ compW_bf, bf16* __restrict__ fc1T,
                               float* __restrict__ cvec,
                               float* __restrict__ stats, float* __restrict__ ebuf) {
  const int b = blockIdx.x;
  if (b < 1024) {
    // fc1_W [4096][1024] f32 -> fc1T [1024][4096] bf16
    __shared__ bf16 tile[64][74];
    const int c0 = (b & 15) * 64;
    const int r0 = (b >> 4) * 64;
    const int col = threadIdx.x & 63;
    const int row4 = threadIdx.x >> 6;
    #pragma unroll
    for (int j = 0; j < 16; ++j) {
      int r = row4 * 16 + j;
      tile[r][col] = __float2bfloat16(fc1_W[(size_t)(r0 + r) * DD + c0 + col]);
    }
    __syncthreads();
    #pragma unroll
    for (int j = 0; j < 16; ++j) {
      int r = row4 * 16 + j;
      fc1T[(size_t)(c0 + r) * HH + r0 + col] = tile[col][r];
    }
  } else if (b < 2048) {
    // cvec[j] = fc1_b . fc2_W[j,:] + fc2_b[j]
    const int j = b - 1024;
    float s = 0.f;
    for (int k = threadIdx.x; k < HH; k += 256) s += fc1_b[k] * fc2_W[(size_t)j * HH + k];
    for (int o = 32; o; o >>= 1) s += __shfl_down(s, o);
    __shared__ float red[4];
    if ((threadIdx.x & 63) == 0) red[threadIdx.x >> 6] = s;
    __syncthreads();
    if (threadIdx.x == 0) cvec[j] = red[0] + red[1] + red[2] + red[3] + fc2_b[j];
  } else {
    // bulk conversions + zero-init (grid-stride over 2048 blocks)
    int i = (b - 2048) * 256 + threadIdx.x;
    const int stride = 2048 * 256;
    const int total = NX4 + NF4 + NC4 + NS4 + NE4;
    const float4 z4 = {0.f, 0.f, 0.f, 0.f};
    for (; i < total; i += stride) {
      if (i < NX4) cvt4(x, x_bf, i);
      else if (i < NX4 + NF4) cvt4(fc2_W, fc2_bf, i - NX4);
      else if (i < NX4 + NF4 + NC4) cvt4(comp_W, compW_bf, i - NX4 - NF4);
      else if (i < NX4 + NF4 + NC4 + NS4) ((float4*)stats)[i - NX4 - NF4 - NC4] = z4;
      else ((float4*)ebuf)[i - NX4 - NF4 - NC4 - NS4] = z4;
    }
  }
}

// sum 4 split-K fp32 partials -> M (=Delta_1, bf16), T = I-M, Tt = T^T
__global__ void mbuild_kernel(const float* __restrict__ Cp,
                              bf16* __restrict__ M, bf16* __restrict__ T, bf16* __restrict__ Tt) {
  __shared__ float tile[64][65];
  int n0 = blockIdx.x * 64, m0 = blockIdx.y * 64;
  int tn = threadIdx.x & 63, tm4 = threadIdx.x >> 6;
  #pragma unroll
  for (int j = 0; j < 16; ++j) {
    int m = tm4 * 16 + j;
    size_t idx = (size_t)(m0 + m) * DD + n0 + tn;
    float v = Cp[idx] + Cp[MSZ + idx] + Cp[2 * MSZ + idx] + Cp[3 * MSZ + idx];
    tile[m][tn] = v;
    float d = ((m0 + m) == (n0 + tn)) ? 1.f : 0.f;
    M[idx] = __float2bfloat16(v);
    T[idx] = __float2bfloat16(d - v);
  }
  __syncthreads();
  #pragma unroll
  for (int j = 0; j < 16; ++j) {
    int r = tm4 * 16 + j;
    float v = tile[tn][r];
    size_t idx = (size_t)(n0 + r) * DD + m0 + tn;
    float d = ((n0 + r) == (m0 + tn)) ? 1.f : 0.f;
    Tt[idx] = __float2bfloat16(d - v);
  }
}

// ---------------- GEMM cores: C[m,n] = sum_k A[m,k]*B[n,k] ----------------
// LDS tiles row-major, 128B pitch, chunk-XOR swizzled: physical 16B-chunk c of row r
// holds logical chunk c ^ (r & 7). global_load_lds dest = wave-uniform base + lane*16B
// -> lane covers (row = lane>>3, phys chunk = lane&7), so source logical chunk =
// (lane&7)^(lane>>3). Reads: fragment rows have row&7 == lane&7, so the unswizzled
// chunk is (logical ^ (lane&7)). Measured 0 LDS bank conflicts with this pattern.

__device__ __forceinline__ void async16(const bf16* g, bf16* l) {
  __builtin_amdgcn_global_load_lds(
      (const __attribute__((address_space(1))) void*)g,
      (__attribute__((address_space(3))) void*)l, 16, 0, 0);
}

// 64x64 tile, 4 waves of 32x32 (2x2 frags) — setup-chain GEMMs (full-chip grids)
__device__ __forceinline__ void gemm_core64(
    const bf16* __restrict__ A, const bf16* __restrict__ B,
    int kBeg, int kEnd, int lda, int ldb, int bm, int bn,
    bf16* As, bf16* Bs, f32x4 acc[2][2])
{
  const int tid  = threadIdx.x;
  const int lane = tid & 63;
  const int wave = tid >> 6;
  const int wm = (wave & 1) * 32;
  const int wn = (wave >> 1) * 32;
  const int lr = lane >> 3;
  const int lcol = ((lane & 7) ^ lr) * 8;
  const bf16* gA = A + (size_t)(bm + wave * 16 + lr) * lda + lcol;
  const bf16* gB = B + (size_t)(bn + wave * 16 + lr) * ldb + lcol;
  bf16* lA = As + wave * 16 * 64;
  bf16* lB = Bs + wave * 16 * 64;

  for (int k0 = kBeg; k0 < kEnd; k0 += 64) {
    #pragma unroll
    for (int it = 0; it < 2; ++it) {
      async16(gA + (size_t)(it * 8) * lda + k0, lA + it * 8 * 64);
      async16(gB + (size_t)(it * 8) * ldb + k0, lB + it * 8 * 64);
    }
    __syncthreads();
    #pragma unroll
    for (int ks = 0; ks < 2; ++ks) {
      bf16x8 av[2], bv[2];
      #pragma unroll
      for (int i = 0; i < 2; ++i) {
        const int rr = i * 16 + (lane & 15);
        const int cc = ((ks * 4 + (lane >> 4)) ^ (lane & 7)) * 8;
        av[i] = *(const bf16x8*)(As + (wm + rr) * 64 + cc);
        bv[i] = *(const bf16x8*)(Bs + (wn + rr) * 64 + cc);
      }
      #pragma unroll
      for (int i = 0; i < 2; ++i)
        #pragma unroll
        for (int j = 0; j < 2; ++j)
          acc[i][j] = __builtin_amdgcn_mfma_f32_16x16x32_bf16(av[i], bv[j], acc[i][j], 0, 0, 0);
    }
    __syncthreads();
  }
}

#define GEMM_PROLOGUE64 \
  alignas(16) __shared__ bf16 As[64 * 64]; \
  alignas(16) __shared__ bf16 Bs[64 * 64]; \
  f32x4 acc[2][2] = {}; \
  const int lane = threadIdx.x & 63; \
  const int wm = ((threadIdx.x >> 6) & 1) * 32; \
  const int wn = ((threadIdx.x >> 6) >> 1) * 32;

// split-K partial GEMM for M = fc1T * fc2 (K=4096 in 4 chunks), fp32 partials.
__global__ __launch_bounds__(256, 4)
void gemm_splitk64(const bf16* __restrict__ A, const bf16* __restrict__ B, float* __restrict__ Cp) {
  GEMM_PROLOGUE64
  const int bm = blockIdx.y * 64, bn = blockIdx.x * 64;
  const int kb = blockIdx.z * (HH / 4);
  gemm_core64(A, B, kb, kb + HH / 4, HH, HH, bm, bn, As, Bs, acc);
  float* C = Cp + (size_t)blockIdx.z * MSZ;
  #pragma unroll
  for (int i = 0; i < 2; ++i)
    #pragma unroll
    for (int j = 0; j < 2; ++j) {
      const int col = bn + wn + j * 16 + (lane & 15);
      #pragma unroll
      for (int r = 0; r < 4; ++r) {
        const int row = bm + wm + i * 16 + (lane >> 4) * 4 + r;
        C[(size_t)row * DD + col] = acc[i][j][r];
      }
    }
}

// dual-output 1024^3: Cn normal + Ct transposed (packed 8B stores). grid (16,16).
__global__ __launch_bounds__(256, 4)
void gemm_dual64(const bf16* __restrict__ A, const bf16* __restrict__ B,
                 bf16* __restrict__ Ct, bf16* __restrict__ Cn) {
  GEMM_PROLOGUE64
  const int bm = blockIdx.y * 64, bn = blockIdx.x * 64;
  gemm_core64(A, B, 0, DD, DD, DD, bm, bn, As, Bs, acc);
  #pragma unroll
  for (int i = 0; i < 2; ++i)
    #pragma unroll
    for (int j = 0; j < 2; ++j) {
      const int col = bn + wn + j * 16 + (lane & 15);
      const int row0 = bm + wm + i * 16 + (lane >> 4) * 4;
      union { bf16 b[4]; uint2 u; } pk;
      #pragma unroll
      for (int r = 0; r < 4; ++r) {
        bf16 v = __float2bfloat16(acc[i][j][r]);
        pk.b[r] = v;
        Cn[(size_t)(row0 + r) * DD + col] = v;
      }
      *(uint2*)(&Ct[(size_t)col * DD + row0]) = pk.u;
    }
}

// batched 1024^3 on 64^2 tiles; grid (16,16,z)
__global__ __launch_bounds__(256, 4)
void gemm_b64(const bf16* __restrict__ A0, long astr, const bf16* __restrict__ B0, long bstr,
              bf16* __restrict__ C0, long cstr) {
  GEMM_PROLOGUE64
  const int z = blockIdx.z;
  const bf16* A = A0 + (size_t)z * astr;
  const bf16* B = B0 + (size_t)z * bstr;
  bf16* C = C0 + (size_t)z * cstr;
  const int bm = blockIdx.y * 64, bn = blockIdx.x * 64;
  gemm_core64(A, B, 0, DD, DD, DD, bm, bn, As, Bs, acc);
  #pragma unroll
  for (int i = 0; i < 2; ++i)
    #pragma unroll
    for (int j = 0; j < 2; ++j) {
      const int col = bn + wn + j * 16 + (lane & 15);
      #pragma unroll
      for (int r = 0; r < 4; ++r) {
        const int row = bm + wm + i * 16 + (lane >> 4) * 4 + r;
        C[(size_t)row * DD + col] = __float2bfloat16(acc[i][j][r]);
      }
    }
}

// T5 = T4*T (acc only) -> Delta2..5 + Bbig0=(I-T5)^T  ||  gemv e2..e5 = (T^i)^T c.
// Flattened grid 320 blocks: b<256 t5-tile, b>=256 gemv job (inputs Pw=T..T4 ready).
__global__ __launch_bounds__(256, 4)
void gemm_t5g(const bf16* __restrict__ A, const bf16* __restrict__ B,
              const bf16* __restrict__ Pw, bf16* __restrict__ Dl, bf16* __restrict__ Bbig0,
              const float* __restrict__ cvec, float* __restrict__ ebuf) {
  GEMM_PROLOGUE64
  const int b = blockIdx.x;
  if (b < 256) {
    const int bm = (b >> 4) * 64, bn = (b & 15) * 64;
    gemm_core64(A, B, 0, DD, DD, DD, bm, bn, As, Bs, acc);
    #pragma unroll
    for (int i = 0; i < 2; ++i)
      #pragma unroll
      for (int j = 0; j < 2; ++j) {
        const int col = bn + wn + j * 16 + (lane & 15);
        const int row0 = bm + wm + i * 16 + (lane >> 4) * 4;
        union { bf16 h[4]; uint2 u; } pk;
        #pragma unroll
        for (int r = 0; r < 4; ++r) {
          const size_t idx = (size_t)(row0 + r) * DD + col;
          const float t1 = __bfloat162float(Pw[idx]);
          const float t2 = __bfloat162float(Pw[MSZ + idx]);
          const float t3 = __bfloat162float(Pw[2 * MSZ + idx]);
          const float t4 = __bfloat162float(Pw[3 * MSZ + idx]);
          const float t5 = acc[i][j][r];
          Dl[idx]           = __float2bfloat16(t1 - t2);
          Dl[MSZ + idx]     = __float2bfloat16(t2 - t3);
          Dl[2 * MSZ + idx] = __float2bfloat16(t3 - t4);
          Dl[3 * MSZ + idx] = __float2bfloat16(t4 - t5);
          pk.h[r] = __float2bfloat16((((row0 + r) == col) ? 1.f : 0.f) - t5);
        }
        *(uint2*)(&Bbig0[(size_t)col * DD + row0]) = pk.u;
      }
  } else {
    // e_{z+2}[j] = sum_k c[k] * T^{z+1}[k][j]  (64 jobs: jg x zp x kg = 4x4x4)
    const int idx = b - 256;
    const int jg = idx & 3, zp = (idx >> 2) & 3, kg = idx >> 4;
    const int j = jg * 256 + threadIdx.x, k0 = kg * 256;
    const bf16* P = Pw + (size_t)zp * MSZ + j;
    float s = 0.f;
    #pragma unroll 8
    for (int k = k0; k < k0 + 256; ++k) s += cvec[k] * __bfloat162float(P[(size_t)k * DD]);
    atomicAdd(&ebuf[zp * DD + j], s);
  }
}

// Bout_z^T = compW_z * Delta_z^T (1280 tile-jobs)  ||  biasall (6144 jobs).
// Independent given {Dbank, ebuf}; merged into one dispatch.
__global__ __launch_bounds__(256, 4)
void boutbias_kernel(const bf16* __restrict__ compWb, const bf16* __restrict__ Dbank,
                     bf16* __restrict__ BbigOut,
                     const float* __restrict__ cvec, const float* __restrict__ ebuf,
                     const float* __restrict__ comp_W, const float* __restrict__ comp_b,
                     float* __restrict__ biasall) {
  GEMM_PROLOGUE64
  const int b = blockIdx.x;
  if (b < 1280) {
    const int z = b >> 8, t = b & 255;
    const int bm = (t >> 4) * 64, bn = (t & 15) * 64;
    gemm_core64(compWb + (size_t)z * MSZ, Dbank + (size_t)z * MSZ, 0, DD, DD, DD,
                bm, bn, As, Bs, acc);
    bf16* C = BbigOut + (size_t)z * MSZ;
    #pragma unroll
    for (int i = 0; i < 2; ++i)
      #pragma unroll
      for (int j = 0; j < 2; ++j) {
        const int col = bn + wn + j * 16 + (lane & 15);
        #pragma unroll
        for (int r = 0; r < 4; ++r) {
          const int row = bm + wm + i * 16 + (lane >> 4) * 4 + r;
          C[(size_t)row * DD + col] = __float2bfloat16(acc[i][j][r]);
        }
      }
  } else {
    const int o = b - 1280;
    const int z = o >> 10, j = o & 1023;
    if (z == 0) {
      if (threadIdx.x == 0)
        biasall[j] = cvec[j] + ebuf[j] + ebuf[DD + j] + ebuf[2 * DD + j] + ebuf[3 * DD + j];
      return;
    }
    const int i = z - 1;
    const float* e = (i == 0) ? cvec : ebuf + (size_t)(i - 1) * DD;
    const float* wr = comp_W + (size_t)i * MSZ + (size_t)j * DD;
    float s = 0.f;
    for (int k = threadIdx.x; k < DD; k += 256) s += e[k] * wr[k];
    for (int o2 = 32; o2; o2 >>= 1) s += __shfl_down(s, o2);
    __shared__ float red[4];
    if ((threadIdx.x & 63) == 0) red[threadIdx.x >> 6] = s;
    __syncthreads();
    if (threadIdx.x == 0)
      biasall[(size_t)z * DD + j] = red[0] + red[1] + red[2] + red[3] + comp_b[(size_t)i * DD + j];
  }
}

// ---------------- main GEMM (round-4 known-good 128^2 core) ----------------

__device__ __forceinline__ void gemm_core_async(
    const bf16* __restrict__ A, const bf16* __restrict__ B,
    int kBeg, int kEnd, int lda, int ldb, int bm, int bn,
    bf16* As, bf16* Bs, f32x4 acc[4][4])
{
  const int tid  = threadIdx.x;
  const int lane = tid & 63;
  const int wave = tid >> 6;
  const int wm = (wave & 1) * 64;
  const int wn = (wave >> 1) * 64;
  const int lr = lane >> 3;                 // row within 8-row DMA group
  const int lcol = ((lane & 7) ^ lr) * 8;   // swizzled source chunk
  const bf16* gA = A + (size_t)(bm + wave * 32 + lr) * lda + lcol;
  const bf16* gB = B + (size_t)(bn + wave * 32 + lr) * ldb + lcol;
  bf16* lA = As + wave * 32 * 64;           // wave-uniform LDS bases
  bf16* lB = Bs + wave * 32 * 64;

  for (int k0 = kBeg; k0 < kEnd; k0 += 64) {
    #pragma unroll
    for (int it = 0; it < 4; ++it) {
      async16(gA + (size_t)(it * 8) * lda + k0, lA + it * 8 * 64);
      async16(gB + (size_t)(it * 8) * ldb + k0, lB + it * 8 * 64);
    }
    __syncthreads();   // compiler emits vmcnt(0) drain before barrier
    #pragma unroll
    for (int ks = 0; ks < 2; ++ks) {
      bf16x8 av[4], bv[4];
      #pragma unroll
      for (int i = 0; i < 4; ++i) {
        const int rr = i * 16 + (lane & 15);
        const int cc = ((ks * 4 + (lane >> 4)) ^ (lane & 7)) * 8;  // unswizzle
        av[i] = *(const bf16x8*)(As + (wm + rr) * 64 + cc);
        bv[i] = *(const bf16x8*)(Bs + (wn + rr) * 64 + cc);
      }
      #pragma unroll
      for (int i = 0; i < 4; ++i)
        #pragma unroll
        for (int j = 0; j < 4; ++j)
          acc[i][j] = __builtin_amdgcn_mfma_f32_16x16x32_bf16(av[i], bv[j], acc[i][j], 0, 0, 0);
    }
    __syncthreads();
  }
}

#define GEMM_PROLOGUE \
  alignas(16) __shared__ bf16 As[128 * 64]; \
  alignas(16) __shared__ bf16 Bs[128 * 64]; \
  f32x4 acc[4][4] = {}; \
  const int lane = threadIdx.x & 63; \
  const int wm = ((threadIdx.x >> 6) & 1) * 64; \
  const int wn = ((threadIdx.x >> 6) >> 1) * 64;

// main GEMM [8192 x 6144 x 1024]: cols 0..1023 -> invtot/nxt; cols 1024+ -> out_z,
// reduced to per-row S,Q (shuffle+atomics) + 1 SIGN BIT per element (ballot words).
// Sign word layout: sgn[(((z*64+rb)*8+cb)*4+wave)*64 + i*16+j*4+r] (u64),
// bit (rg*16+c15) = sign(out[row,col]).
__global__ __launch_bounds__(256, 2)
void gemm_main(const bf16* __restrict__ A, const bf16* __restrict__ Bb,
               const float* __restrict__ biasall, const bf16* __restrict__ xb,
               float* __restrict__ invtot, float* __restrict__ nxtf,
               unsigned long long* __restrict__ sgn,
               float* __restrict__ Srow, float* __restrict__ Qrow) {
  GEMM_PROLOGUE
  const int bm = blockIdx.y * 128, bn = blockIdx.x * 128;
  gemm_core_async(A, Bb + (size_t)(bn >> 10) * MSZ, 0, DD, DD, DD, bm, bn & (DD - 1), As, Bs, acc);

  if (bn < DD) {
    #pragma unroll
    for (int i = 0; i < 4; ++i)
      #pragma unroll
      for (int j = 0; j < 4; ++j) {
        const int col = bn + wn + j * 16 + (lane & 15);
        const float bj = biasall[col];
        #pragma unroll
        for (int r = 0; r < 4; ++r) {
          const int row = bm + wm + i * 16 + (lane >> 4) * 4 + r;
          const float v = acc[i][j][r] + bj;
          const size_t idx = (size_t)row * DD + col;
          invtot[idx] = v;
          nxtf[idx] = __bfloat162float(xb[idx]) - v;   // xb rows are L2-hot (A-tile)
        }
      }
  } else {
    const int z = (bn >> 10) - 1;
    const int rb = bm >> 7;
    const int cb = (bn & (DD - 1)) >> 7;
    const int wave = threadIdx.x >> 6;
    unsigned long long keep = 0ULL;
    float sv[4][4] = {}, qv[4][4] = {};
    #pragma unroll
    for (int i = 0; i < 4; ++i)
      #pragma unroll
      for (int j = 0; j < 4; ++j) {
        const int colg = bn + wn + j * 16 + (lane & 15);
        const float bj = biasall[colg];
        #pragma unroll
        for (int r = 0; r < 4; ++r) {
          const float v = acc[i][j][r] + bj;
          const unsigned long long bal = __ballot(v < 0.f);
          if (lane == i * 16 + j * 4 + r) keep = bal;   // idx compile-time per unroll
          sv[i][r] += v;
          qv[i][r] += v * v;
        }
      }
    const size_t wbase = ((((size_t)z * 64 + rb) * 8 + cb) * 4 + wave) * 64;
    sgn[wbase + lane] = keep;                            // 512 B/wave, coalesced
    #pragma unroll
    for (int i = 0; i < 4; ++i)
      #pragma unroll
      for (int r = 0; r < 4; ++r) {
        float s = sv[i][r], q = qv[i][r];
        #pragma unroll
        for (int off = 1; off < 16; off <<= 1) { s += __shfl_xor(s, off); q += __shfl_xor(q, off); }
        if ((lane & 15) == 0) {
          const int row = bm + wm + i * 16 + (lane >> 4) * 4 + r;
          atomicAdd(&Srow[(size_t)z * NR + row], s);
          atomicAdd(&Qrow[(size_t)z * NR + row], q);
        }
      }
  }
}

// ---------------- loss ----------------

// Dtot[z][col] += sum_n |c[n,col]-c[n-1,col]|, c[n,col] = +-r[n] by sign bit.
__global__ void losssign_kernel(const unsigned long long* __restrict__ sgn,
                                const float* __restrict__ Srow, const float* __restrict__ Qrow,
                                float* __restrict__ Dtot) {
  const int z = blockIdx.y;
  const int cg = blockIdx.x;            // 64-col group
  const int n0 = blockIdx.z * 1024;
  __shared__ float rsh[1025];
  const float* S = Srow + (size_t)z * NR;
  const float* Q = Qrow + (size_t)z * NR;
  for (int t = threadIdx.x; t < 1025; t += 256) {
    int n = n0 + t; if (n > NR - 1) n = NR - 1;
    rsh[t] = S[n] * rsqrtf(Q[n]) * 0.03125f;   // r[n] = S/(32*sqrt(Q))
  }
  __syncthreads();
  const int c = threadIdx.x & 63;
  const int q = threadIdx.x >> 6;
  const int col = cg * 64 + c;
  const int cb = col >> 7;
  const int wsel = (col >> 6) & 1;      // wn half -> wave bit 1
  const int jf = (col >> 4) & 3;
  const int c15 = col & 15;
  const size_t zbase = (size_t)z * 64 * 8 * 4 * 64;
  const int ns = n0 + q * 256;
  int ne = ns + 256; if (ne > NR - 1) ne = NR - 1;

  auto cval = [&](int n) -> float {
    const int rbk = n >> 7, nl = n & 127;
    const int wave = (nl >> 6) | (wsel << 1);
    const int i = (nl >> 4) & 3, rg = (nl >> 2) & 3, r = nl & 3;
    const size_t widx = zbase + ((((size_t)rbk * 8 + cb) * 4 + wave) * 64)
                      + i * 16 + jf * 4 + r;
    const unsigned long long wv = sgn[widx];
    const float rv = rsh[n - n0];
    return ((wv >> (rg * 16 + c15)) & 1ULL) ? -rv : rv;
  };

  float d = 0.f;
  float cprev = cval(ns);
  for (int n = ns + 1; n <= ne; ++n) {
    const float cn = cval(n);
    d += fabsf(cn - cprev);
    cprev = cn;
  }
  atomicAdd(&Dtot[z * DD + col], d);
}

__global__ void writeloss_kernel(const float* __restrict__ Dtot, float* __restrict__ out) {
  int idx = blockIdx.x * 256 + threadIdx.x;
  int j = idx & (DD - 1);
  out[idx] = Dtot[j] + Dtot[DD + j] + Dtot[2 * DD + j] + Dtot[3 * DD + j] + Dtot[4 * DD + j];
}

// ---------------- launch ----------------

extern "C" void kernel_launch(void* const* d_in, const int* in_sizes, int n_in,
                              void* d_out, int out_size, void* d_ws, size_t ws_size,
                              hipStream_t stream) {
  const float* x      = (const float*)d_in[0];
  const float* fc1_W  = (const float*)d_in[1];
  const float* fc1_b  = (const float*)d_in[2];
  const float* fc2_W  = (const float*)d_in[3];
  const float* fc2_b  = (const float*)d_in[4];
  const float* comp_W = (const float*)d_in[5];
  const float* comp_b = (const float*)d_in[6];

  float* invtot  = (float*)d_out;
  float* nxtf    = invtot + (size_t)NR * DD;
  float* lossout = invtot + (size_t)2 * NR * DD;

  char* w = (char*)d_ws;
  auto alloc = [&](size_t bytes) { char* p = w; w += (bytes + 255) & ~(size_t)255; return p; };
  bf16* x_bf     = (bf16*)alloc((size_t)NR * DD * 2);          // 16 MB
  bf16* fc1T_bf  = (bf16*)alloc((size_t)DD * HH * 2);          // 8 MB
  bf16* fc2_bf   = (bf16*)alloc((size_t)DD * HH * 2);          // 8 MB
  bf16* compW_bf = (bf16*)alloc((size_t)NL * MSZ * 2);         // 10 MB
  bf16* Dbank    = (bf16*)alloc((size_t)5 * MSZ * 2);          // [Delta1=M, D2..D5] 10 MB
  bf16* M_bf = Dbank;
  bf16* Dl   = Dbank + MSZ;
  bf16* Tt_buf   = (bf16*)alloc((size_t)2 * MSZ * 2);          // [Tt, T2t] 4 MB
  bf16* Pw       = (bf16*)alloc((size_t)4 * MSZ * 2);          // [T, T2, T3, T4] 8 MB
  bf16* Bbig     = (bf16*)alloc((size_t)6 * MSZ * 2);          // 12 MB
  unsigned long long* sgn = (unsigned long long*)alloc((size_t)NL * 64 * 8 * 4 * 64 * 8); // 5 MB
  float* Cp      = (float*)alloc((size_t)4 * MSZ * 4);         // 16 MB split-K partials
  float* cvec    = (float*)alloc(DD * 4);
  float* ebuf    = (float*)alloc((size_t)4 * DD * 4);
  float* biasall = (float*)alloc((size_t)6 * DD * 4);
  float* stats   = (float*)alloc((size_t)(NL * DD + 2 * NL * NR) * 4);
  float* Dtot = stats;
  float* Srow = stats + NL * DD;
  float* Qrow = Srow + (size_t)NL * NR;
  (void)ws_size; (void)in_sizes; (void)n_in; (void)out_size;

  // 1. all prep in one dispatch: transpose || cvec || bulk cvt + zeros
  prepall_kernel<<<4096, 256, 0, stream>>>(x, fc2_W, comp_W, fc1_W, fc1_b, fc2_b,
                                           x_bf, fc2_bf, compW_bf, fc1T_bf, cvec, stats, ebuf);
  // 2. M = fc1^T fc2^T (K=4096) via split-K(4) on 64^2 tiles (1024 blocks)
  gemm_splitk64<<<dim3(16, 16, 4), 256, 0, stream>>>(fc1T_bf, fc2_bf, Cp);
  // 3. combine partials -> M(=Delta1)/T/Tt
  mbuild_kernel<<<dim3(16, 16), 256, 0, stream>>>(Cp, M_bf, Pw, Tt_buf);
  // 4. T2 (dual layout: Pw+MSZ normal, Tt_buf+MSZ transposed)
  gemm_dual64<<<dim3(16, 16), 256, 0, stream>>>(Pw, Tt_buf, Tt_buf + MSZ, Pw + MSZ);
  // 5. T3 = T2*T, T4 = T2*T2 (batched)
  gemm_b64<<<dim3(16, 16, 2), 256, 0, stream>>>(Pw + MSZ, 0, Tt_buf, MSZ, Pw + 2 * MSZ, MSZ);
  // 6. T5 -> Delta2..5 + Bbig0 = (I-T5)^T  ||  gemv e2..e5
  gemm_t5g<<<320, 256, 0, stream>>>(Pw + 3 * MSZ, Tt_buf, Pw, Dl, Bbig, cvec, ebuf);
  // 7. Bout_z^T = compW_z * Delta_z^T  ||  biasall
  boutbias_kernel<<<1280 + 6 * DD, 256, 0, stream>>>(compW_bf, Dbank, Bbig + MSZ,
                                                     cvec, ebuf, comp_W, comp_b, biasall);
  // 8. main GEMM (round-4 128^2 core)
  gemm_main<<<dim3(6 * DD / 128, NR / 128), 256, 0, stream>>>(
      x_bf, Bbig, biasall, x_bf, invtot, nxtf, sgn, Srow, Qrow);
  // 9-10. loss
  losssign_kernel<<<dim3(16, NL, 8), 256, 0, stream>>>(sgn, Srow, Qrow, Dtot);
  writeloss_kernel<<<MSZ / 256, 256, 0, stream>>>(Dtot, lossout);
}